// Round 1
// baseline (264.823 us; speedup 1.0000x reference)
//
#include <hip/hip_runtime.h>
#include <hip/hip_bf16.h>
#include <math.h>

// LoRA attention, MI355X bf16-MFMA pipeline.
// Stages: cast x->bf16 | fold Weff=W+B@A (bf16) | 3 proj GEMMs (V transposed)
//         | scores GEMM (bf16 P) | row softmax in-place | PV GEMM (fp32 out)

typedef __attribute__((ext_vector_type(4))) float f32x4;
typedef __attribute__((ext_vector_type(8))) short bf8;   // 8 x bf16
typedef __attribute__((ext_vector_type(4))) short bf4;   // 4 x bf16

__device__ __forceinline__ float bf2f(unsigned short b) {
  union { unsigned u; float f; } c; c.u = ((unsigned)b) << 16; return c.f;
}
__device__ __forceinline__ unsigned short f2bf(float f) {
  union { float f; unsigned u; } c; c.f = f;
  return (unsigned short)((c.u + 0x7fffu + ((c.u >> 16) & 1u)) >> 16);
}
__device__ __forceinline__ void gload16(const void* g, void* l) {
  __builtin_amdgcn_global_load_lds((const __attribute__((address_space(1))) void*)g,
                                   (__attribute__((address_space(3))) void*)l, 16, 0, 0);
}

// ---------------- cast fp32 -> bf16, 8 elems/thread ----------------
__global__ __launch_bounds__(256)
void k_cast(const float* __restrict__ x, __hip_bfloat16* __restrict__ o) {
  long i = ((long)blockIdx.x * 256 + threadIdx.x) * 8;
  float4 a = *(const float4*)&x[i];
  float4 b = *(const float4*)&x[i + 4];
  union { bf8 v; unsigned short h[8]; } u;
  u.h[0] = f2bf(a.x); u.h[1] = f2bf(a.y); u.h[2] = f2bf(a.z); u.h[3] = f2bf(a.w);
  u.h[4] = f2bf(b.x); u.h[5] = f2bf(b.y); u.h[6] = f2bf(b.z); u.h[7] = f2bf(b.w);
  *(bf8*)&o[i] = u.v;
}

// ---------------- Weff = W + B@A  (fp32 math, bf16 out) ----------------
__global__ __launch_bounds__(256)
void k_fold(const float* __restrict__ W, const float* __restrict__ A,
            const float* __restrict__ Bl, __hip_bfloat16* __restrict__ out) {
  int idx = blockIdx.x * 256 + threadIdx.x;     // 768*768 total
  int d = idx % 768, o = idx / 768;
  float acc = W[idx];
  #pragma unroll
  for (int r = 0; r < 32; ++r) acc += Bl[o * 32 + r] * A[r * 768 + d];
  out[idx] = __float2bfloat16(acc);
}

// ---------------- GEMM: Out[m][n] = scale * sum_k A[m][k]*B[n][k] (+bias[n]) ----------
// m97 structure: 128x128 tile, BK=32, 4 waves (2x2), 4x4 16x16x32 frags/wave.
// OUT_MODE: 0 = fp32 row-major, 1 = bf16 row-major, 2 = bf16 transposed ([n][m])
template<int OUT_MODE>
__global__ __launch_bounds__(256, 2)
void k_gemm(const __hip_bfloat16* __restrict__ Ag, const __hip_bfloat16* __restrict__ Bg,
            const float* __restrict__ bias, void* __restrict__ Og,
            int K, int lda, int ldb, int ldo,
            long sA, long sB, long sO, float scale)
{
  __shared__ __hip_bfloat16 As[128 * 32];
  __shared__ __hip_bfloat16 Bs[128 * 32];
  const int tid = threadIdx.x;
  const int wave = tid >> 6, lane = tid & 63;
  const long z = blockIdx.z;
  const __hip_bfloat16* A = Ag + z * sA;
  const __hip_bfloat16* B = Bg + z * sB;
  const long arow0 = (long)blockIdx.x * 128;
  const long brow0 = (long)blockIdx.y * 128;

  f32x4 acc[4][4] = {};

  // staging: wave w covers tile elems [w*1024, w*1024+1024), 2 issues of 512 elems
  const int e0 = wave * 1024 + lane * 8;
  const int r0 = e0 >> 5, c0 = e0 & 31;
  const int e1 = e0 + 512;
  const int r1 = e1 >> 5, c1 = e1 & 31;

  const int wm = wave >> 1, wn = wave & 1;
  const int arow_f = wm * 64 + (lane & 15);
  const int brow_f = wn * 64 + (lane & 15);
  const int kf = (lane >> 4) * 8;

  for (int k0 = 0; k0 < K; k0 += 32) {
    __syncthreads();  // previous ds_reads done before overwrite
    gload16(A + (arow0 + r0) * (long)lda + k0 + c0, As + wave * 1024);
    gload16(A + (arow0 + r1) * (long)lda + k0 + c1, As + wave * 1024 + 512);
    gload16(B + (brow0 + r0) * (long)ldb + k0 + c0, Bs + wave * 1024);
    gload16(B + (brow0 + r1) * (long)ldb + k0 + c1, Bs + wave * 1024 + 512);
    __syncthreads();  // drains vmcnt(0): tile visible

    bf8 af[4], bfv[4];
    #pragma unroll
    for (int m = 0; m < 4; ++m) af[m]  = *(const bf8*)&As[(arow_f + m * 16) * 32 + kf];
    #pragma unroll
    for (int n = 0; n < 4; ++n) bfv[n] = *(const bf8*)&Bs[(brow_f + n * 16) * 32 + kf];
    #pragma unroll
    for (int m = 0; m < 4; ++m)
      #pragma unroll
      for (int n = 0; n < 4; ++n)
        acc[m][n] = __builtin_amdgcn_mfma_f32_16x16x32_bf16(af[m], bfv[n], acc[m][n], 0, 0, 0);
  }

  // epilogue: C/D map col=lane&15, row=(lane>>4)*4+r  [m89-verified]
  #pragma unroll
  for (int m = 0; m < 4; ++m) {
    const long rb = arow0 + wm * 64 + m * 16 + ((lane >> 4) << 2);
    #pragma unroll
    for (int n = 0; n < 4; ++n) {
      const long cb = brow0 + wn * 64 + n * 16 + (lane & 15);
      const float bv = bias ? bias[cb] : 0.0f;
      if constexpr (OUT_MODE == 0) {
        float* O = (float*)Og + z * sO;
        #pragma unroll
        for (int r = 0; r < 4; ++r) O[(rb + r) * (long)ldo + cb] = acc[m][n][r] * scale + bv;
      } else if constexpr (OUT_MODE == 1) {
        __hip_bfloat16* O = (__hip_bfloat16*)Og + z * sO;
        #pragma unroll
        for (int r = 0; r < 4; ++r)
          *(unsigned short*)&O[(rb + r) * (long)ldo + cb] = f2bf(acc[m][n][r] * scale + bv);
      } else {
        __hip_bfloat16* O = (__hip_bfloat16*)Og + z * sO;
        bf4 v;
        #pragma unroll
        for (int r = 0; r < 4; ++r) v[r] = (short)f2bf(acc[m][n][r] * scale + bv);
        *(bf4*)&O[cb * (long)ldo + rb] = v;   // [n][m] layout, 4 bf16 contiguous along m
      }
    }
  }
}

// ---------------- row softmax in place, row = 4096 bf16 ----------------
__global__ __launch_bounds__(256)
void k_softmax(__hip_bfloat16* __restrict__ P) {
  const int S = 4096;
  __hip_bfloat16* p = P + (long)blockIdx.x * S;
  const int tid = threadIdx.x, lane = tid & 63, wave = tid >> 6;
  __shared__ float red[8];
  float x[16];
  bf8 a = *(const bf8*)&p[tid * 16];
  bf8 b = *(const bf8*)&p[tid * 16 + 8];
  #pragma unroll
  for (int j = 0; j < 8; ++j) { x[j] = bf2f((unsigned short)a[j]); x[8 + j] = bf2f((unsigned short)b[j]); }
  float mx = x[0];
  #pragma unroll
  for (int j = 1; j < 16; ++j) mx = fmaxf(mx, x[j]);
  #pragma unroll
  for (int o = 32; o; o >>= 1) mx = fmaxf(mx, __shfl_xor(mx, o));
  if (lane == 0) red[wave] = mx;
  __syncthreads();
  mx = fmaxf(fmaxf(red[0], red[1]), fmaxf(red[2], red[3]));
  float s = 0.0f;
  #pragma unroll
  for (int j = 0; j < 16; ++j) { x[j] = __expf(x[j] - mx); s += x[j]; }
  #pragma unroll
  for (int o = 32; o; o >>= 1) s += __shfl_xor(s, o);
  if (lane == 0) red[4 + wave] = s;
  __syncthreads();
  const float inv = 1.0f / (red[4] + red[5] + red[6] + red[7]);
  union { bf8 v; unsigned short h[8]; } u0, u1;
  #pragma unroll
  for (int j = 0; j < 8; ++j) { u0.h[j] = f2bf(x[j] * inv); u1.h[j] = f2bf(x[8 + j] * inv); }
  *(bf8*)&p[tid * 16] = u0.v;
  *(bf8*)&p[tid * 16 + 8] = u1.v;
}

extern "C" void kernel_launch(void* const* d_in, const int* in_sizes, int n_in,
                              void* d_out, int out_size, void* d_ws, size_t ws_size,
                              hipStream_t stream) {
  const float* x  = (const float*)d_in[0];
  const float* Wq = (const float*)d_in[1]; const float* bq = (const float*)d_in[2];
  const float* Wk = (const float*)d_in[3]; const float* bk = (const float*)d_in[4];
  const float* Wv = (const float*)d_in[5]; const float* bv = (const float*)d_in[6];
  const float* Aq = (const float*)d_in[7]; const float* Bq = (const float*)d_in[8];
  const float* Ak = (const float*)d_in[9]; const float* Bk = (const float*)d_in[10];
  const float* Av = (const float*)d_in[11]; const float* Bv = (const float*)d_in[12];

  const int  D = 768, S = 4096;
  const long BS = 8192;                       // B*S rows
  // ws layout (bf16), total ~121 MB
  __hip_bfloat16* Xb = (__hip_bfloat16*)d_ws;          // [8192][768]
  __hip_bfloat16* We = Xb + BS * D;                    // 3 x [768][768]
  __hip_bfloat16* Qb = We + 3L * D * D;                // [8192][768]
  __hip_bfloat16* Kb = Qb + BS * D;                    // [8192][768]
  __hip_bfloat16* Vt = Kb + BS * D;                    // [768][8192]  (transposed V)
  __hip_bfloat16* Pb = Vt + BS * D;                    // [2][4096][4096]
  float* out = (float*)d_out;

  k_cast<<<3072, 256, 0, stream>>>(x, Xb);
  k_fold<<<2304, 256, 0, stream>>>(Wq, Aq, Bq, We);
  k_fold<<<2304, 256, 0, stream>>>(Wk, Ak, Bk, We + 589824);
  k_fold<<<2304, 256, 0, stream>>>(Wv, Av, Bv, We + 2 * 589824);

  // projections: M=8192, N=768, K=768
  k_gemm<1><<<dim3(64, 6, 1), 256, 0, stream>>>(Xb, We,            bq, Qb, 768, 768, 768, 768, 0, 0, 0, 1.0f);
  k_gemm<1><<<dim3(64, 6, 1), 256, 0, stream>>>(Xb, We + 589824,   bk, Kb, 768, 768, 768, 768, 0, 0, 0, 1.0f);
  k_gemm<2><<<dim3(64, 6, 1), 256, 0, stream>>>(Xb, We + 1179648,  bv, Vt, 768, 768, 768, 8192, 0, 0, 0, 1.0f);

  // scores: per batch M=N=4096, K=768, scale 1/sqrt(768), bf16 out
  const float sc = 0.036084391824351615f;
  k_gemm<1><<<dim3(32, 32, 2), 256, 0, stream>>>(Qb, Kb, nullptr, Pb, 768, 768, 768, 4096,
                                                 (long)S * D, (long)S * D, (long)S * S, sc);
  // softmax over 8192 rows of 4096
  k_softmax<<<8192, 256, 0, stream>>>(Pb);
  // PV: per batch M=4096, N=768, K=4096; B = Vt rows (ldb=8192, batch offset 4096 cols)
  k_gemm<0><<<dim3(32, 6, 2), 256, 0, stream>>>(Pb, Vt, nullptr, out, 4096, 4096, 8192, 768,
                                                (long)S * S, (long)S, (long)S * D, 1.0f);
}